// Round 3
// baseline (66.578 us; speedup 1.0000x reference)
//
#include <hip/hip_runtime.h>

// y = relu(x @ W1 + b1) @ W2 + b2  via bf16 MFMA (fp32 accumulate).
// x: [B, 64] f32, W1: [64, 32], b1: [32], W2: [32, 10], b2: [10], y: [B, 10] f32.
//
// Per wave-tile (16 batch rows):
//   A-frag (x):  lane l holds row (l&15), k = 8*(l>>4)+i  (i=0..7), two K-halves.
//   B-frag (W):  lane l holds col (l&15), k = 8*(l>>4)+i. Built once per wave.
//   C/D layout:  col = lane&15, row = (lane>>4)*4 + reg.
// h transpose (C-layout -> A-layout) via tiny per-wave LDS bounce. h rows are
// stored PACKED: dword at byte 4*c of a row holds (h[c], h[c+16]) -> one
// cvt-pk + one ds_write_b32 per r (instead of 2x ds_write_b16). The k-order
// of a row becomes col(p) = (p&1)*16 + (p>>1); W2's fragment uses the same
// permutation, so the MFMA k-reduction is unaffected.
//
// Register double-buffer: tile t+1's x loads issue at the top of iteration t,
// before the LDS-order asm clobbers, so HBM latency hides under MFMA/LDS work.

#define N_IN  64
#define N_MID 32
#define N_OUT 10

#define WAVES_PER_BLOCK 4
#define TILES_PER_WAVE  4
#define ROWS_PER_TILE   16
#define ROWS_PER_BLOCK  (WAVES_PER_BLOCK * TILES_PER_WAVE * ROWS_PER_TILE)  // 256
#define H_STRIDE        80  // bytes per h-row in LDS (64 data + 16 pad)

typedef short bf16x8 __attribute__((ext_vector_type(8)));
typedef float f32x4  __attribute__((ext_vector_type(4)));

static __device__ __forceinline__ short f2bf(float f) {
    __bf16 h = (__bf16)f;
    return __builtin_bit_cast(short, h);
}

static __device__ __forceinline__ unsigned pk2bf(float lo, float hi) {
    unsigned l = (unsigned short)__builtin_bit_cast(unsigned short, (__bf16)lo);
    unsigned h = (unsigned short)__builtin_bit_cast(unsigned short, (__bf16)hi);
    return (h << 16) | l;
}

__global__ __launch_bounds__(256)
void livenet_mfma(const float* __restrict__ x,
                  const float* __restrict__ W1,
                  const float* __restrict__ b1,
                  const float* __restrict__ W2,
                  const float* __restrict__ b2,
                  float* __restrict__ out,
                  int batch) {
    __shared__ unsigned char h_lds_all[WAVES_PER_BLOCK][ROWS_PER_TILE * H_STRIDE];

    const int lane = threadIdx.x & 63;
    const int wave = threadIdx.x >> 6;
    const int g    = lane >> 4;   // 0..3 : k-group
    const int c    = lane & 15;   // 0..15: row (A) / col (B,C)

    unsigned char* h_lds = h_lds_all[wave];

    // ---- weight fragments, once per wave ----
    bf16x8 w1f[2][2];  // [n-tile][k-half]
    #pragma unroll
    for (int n = 0; n < 2; ++n)
        #pragma unroll
        for (int p = 0; p < 2; ++p)
            #pragma unroll
            for (int i = 0; i < 8; ++i) {
                int k = p * 32 + 8 * g + i;
                w1f[n][p][i] = f2bf(W1[k * N_MID + n * 16 + c]);
            }

    // W2 fragment in the PACKED-h k-order: position p holds col (p&1)*16+(p>>1).
    bf16x8 w2f;
    #pragma unroll
    for (int i = 0; i < 8; ++i) {
        int kpos = 8 * g + i;
        int col  = (kpos & 1) * 16 + (kpos >> 1);
        w2f[i] = (c < N_OUT) ? f2bf(W2[col * N_OUT + c]) : (short)0;
    }

    const float b1v0 = b1[c];
    const float b1v1 = b1[16 + c];
    const float b2v  = (c < N_OUT) ? b2[c] : 0.0f;

    const size_t wave_row0 = (size_t)blockIdx.x * ROWS_PER_BLOCK
                           + (size_t)wave * (TILES_PER_WAVE * ROWS_PER_TILE);
    const bool full = (wave_row0 + TILES_PER_WAVE * ROWS_PER_TILE) <= (size_t)batch;

    const float* xbase = x + (wave_row0 + (size_t)c) * N_IN + 8 * g;

    if (full) {
        // ---- prefetch tile 0 ----
        float4 v0 = *(const float4*)(xbase + 0);
        float4 v1 = *(const float4*)(xbase + 4);
        float4 v2 = *(const float4*)(xbase + 32);
        float4 v3 = *(const float4*)(xbase + 36);

        #pragma unroll
        for (int t = 0; t < TILES_PER_WAVE; ++t) {
            // ---- prefetch tile t+1 (independent; issues before compute) ----
            float4 n0 = v0, n1 = v1, n2 = v2, n3 = v3;
            if (t + 1 < TILES_PER_WAVE) {
                const float* xp = xbase + (size_t)(t + 1) * ROWS_PER_TILE * N_IN;
                n0 = *(const float4*)(xp + 0);
                n1 = *(const float4*)(xp + 4);
                n2 = *(const float4*)(xp + 32);
                n3 = *(const float4*)(xp + 36);
            }

            // ---- layer 1 ----
            bf16x8 a0, a1;
            a0[0] = f2bf(v0.x); a0[1] = f2bf(v0.y); a0[2] = f2bf(v0.z); a0[3] = f2bf(v0.w);
            a0[4] = f2bf(v1.x); a0[5] = f2bf(v1.y); a0[6] = f2bf(v1.z); a0[7] = f2bf(v1.w);
            a1[0] = f2bf(v2.x); a1[1] = f2bf(v2.y); a1[2] = f2bf(v2.z); a1[3] = f2bf(v2.w);
            a1[4] = f2bf(v3.x); a1[5] = f2bf(v3.y); a1[6] = f2bf(v3.z); a1[7] = f2bf(v3.w);

            f32x4 acc0 = {b1v0, b1v0, b1v0, b1v0};
            f32x4 acc1 = {b1v1, b1v1, b1v1, b1v1};
            acc0 = __builtin_amdgcn_mfma_f32_16x16x32_bf16(a0, w1f[0][0], acc0, 0, 0, 0);
            acc0 = __builtin_amdgcn_mfma_f32_16x16x32_bf16(a1, w1f[0][1], acc0, 0, 0, 0);
            acc1 = __builtin_amdgcn_mfma_f32_16x16x32_bf16(a0, w1f[1][0], acc1, 0, 0, 0);
            acc1 = __builtin_amdgcn_mfma_f32_16x16x32_bf16(a1, w1f[1][1], acc1, 0, 0, 0);

            // ---- relu + packed transpose write: dword = (h[c], h[c+16]) ----
            #pragma unroll
            for (int r = 0; r < 4; ++r) {
                const int rowr = 4 * g + r;
                *(unsigned*)(h_lds + rowr * H_STRIDE + 4 * c) =
                    pk2bf(fmaxf(acc0[r], 0.0f), fmaxf(acc1[r], 0.0f));
            }
            __asm__ volatile("" ::: "memory");

            // ---- layer 2 ----
            const bf16x8 hfrag = *(const bf16x8*)(h_lds + c * H_STRIDE + 16 * g);
            f32x4 acc2 = {b2v, b2v, b2v, b2v};
            acc2 = __builtin_amdgcn_mfma_f32_16x16x32_bf16(hfrag, w2f, acc2, 0, 0, 0);

            __asm__ volatile("" ::: "memory");

            // ---- store ----
            if (c < N_OUT) {
                const size_t rb = wave_row0 + (size_t)t * ROWS_PER_TILE;
                float* op = out + (rb + 4 * g) * N_OUT + c;
                op[0 * N_OUT] = acc2[0];
                op[1 * N_OUT] = acc2[1];
                op[2 * N_OUT] = acc2[2];
                op[3 * N_OUT] = acc2[3];
            }

            v0 = n0; v1 = n1; v2 = n2; v3 = n3;
        }
    } else {
        // ---- tail path (partial blocks; not taken for batch % 256 == 0) ----
        for (int t = 0; t < TILES_PER_WAVE; ++t) {
            const size_t rb = wave_row0 + (size_t)t * ROWS_PER_TILE;
            if (rb + ROWS_PER_TILE > (size_t)batch) break;

            const float* xp = xbase + (size_t)t * ROWS_PER_TILE * N_IN;
            float4 v0 = *(const float4*)(xp + 0);
            float4 v1 = *(const float4*)(xp + 4);
            float4 v2 = *(const float4*)(xp + 32);
            float4 v3 = *(const float4*)(xp + 36);

            bf16x8 a0, a1;
            a0[0] = f2bf(v0.x); a0[1] = f2bf(v0.y); a0[2] = f2bf(v0.z); a0[3] = f2bf(v0.w);
            a0[4] = f2bf(v1.x); a0[5] = f2bf(v1.y); a0[6] = f2bf(v1.z); a0[7] = f2bf(v1.w);
            a1[0] = f2bf(v2.x); a1[1] = f2bf(v2.y); a1[2] = f2bf(v2.z); a1[3] = f2bf(v2.w);
            a1[4] = f2bf(v3.x); a1[5] = f2bf(v3.y); a1[6] = f2bf(v3.z); a1[7] = f2bf(v3.w);

            f32x4 acc0 = {b1v0, b1v0, b1v0, b1v0};
            f32x4 acc1 = {b1v1, b1v1, b1v1, b1v1};
            acc0 = __builtin_amdgcn_mfma_f32_16x16x32_bf16(a0, w1f[0][0], acc0, 0, 0, 0);
            acc0 = __builtin_amdgcn_mfma_f32_16x16x32_bf16(a1, w1f[0][1], acc0, 0, 0, 0);
            acc1 = __builtin_amdgcn_mfma_f32_16x16x32_bf16(a0, w1f[1][0], acc1, 0, 0, 0);
            acc1 = __builtin_amdgcn_mfma_f32_16x16x32_bf16(a1, w1f[1][1], acc1, 0, 0, 0);

            #pragma unroll
            for (int r = 0; r < 4; ++r) {
                const int rowr = 4 * g + r;
                *(unsigned*)(h_lds + rowr * H_STRIDE + 4 * c) =
                    pk2bf(fmaxf(acc0[r], 0.0f), fmaxf(acc1[r], 0.0f));
            }
            __asm__ volatile("" ::: "memory");

            const bf16x8 hfrag = *(const bf16x8*)(h_lds + c * H_STRIDE + 16 * g);
            f32x4 acc2 = {b2v, b2v, b2v, b2v};
            acc2 = __builtin_amdgcn_mfma_f32_16x16x32_bf16(hfrag, w2f, acc2, 0, 0, 0);

            __asm__ volatile("" ::: "memory");

            if (c < N_OUT) {
                float* op = out + (rb + 4 * g) * N_OUT + c;
                op[0 * N_OUT] = acc2[0];
                op[1 * N_OUT] = acc2[1];
                op[2 * N_OUT] = acc2[2];
                op[3 * N_OUT] = acc2[3];
            }
        }
    }
}

extern "C" void kernel_launch(void* const* d_in, const int* in_sizes, int n_in,
                              void* d_out, int out_size, void* d_ws, size_t ws_size,
                              hipStream_t stream) {
    const float* x  = (const float*)d_in[0];
    const float* W1 = (const float*)d_in[1];
    const float* b1 = (const float*)d_in[2];
    const float* W2 = (const float*)d_in[3];
    const float* b2 = (const float*)d_in[4];
    float* out = (float*)d_out;

    int batch = in_sizes[0] / N_IN;                             // 1048576
    int grid  = (batch + ROWS_PER_BLOCK - 1) / ROWS_PER_BLOCK;  // 4096
    livenet_mfma<<<grid, 256, 0, stream>>>(x, W1, b1, W2, b2, out, batch);
}

// Round 4
// 62.491 us; speedup vs baseline: 1.0654x; 1.0654x over previous
//
#include <hip/hip_runtime.h>

// y = relu(x @ W1 + b1) @ W2 + b2  via bf16 MFMA (fp32 accumulate).
// x: [B, 64] f32, W1: [64, 32], b1: [32], W2: [32, 10], b2: [10], y: [B, 10] f32.
//
// Round 4: coalesced x staging.
//   - Per 16-row tile, x (4KB) is staged to LDS with 4x global_load_lds
//     (width 16): each instruction is one contiguous, fully-consumed 1KB
//     request (16 lines touched once each) instead of 16B-granular scatter
//     over 4KB (32 line-touches/instr, each line hit by 2 instrs).
//   - LDS dest is LINEAR (HW: base + lane*16). The bank-conflict swizzle is
//     applied as a permutation of the GLOBAL source (chunk m' at row r holds
//     global chunk m' ^ (r&7)) and mirrored on the ds_read side. Fragment
//     reads then hit 8 bank-groups 2-way -> conflict-free in practice.
//   - Double-buffered stage + counted s_waitcnt vmcnt(4): the 4 newest
//     outstanding VMEM ops are this tile's y-stores; the staged loads for
//     tile t+1 are guaranteed complete without draining stores.
//   - A-frag (x): lane l = (g,c): row c, k = 8g+i (i=0..7), two K-halves.
//     B-frag (W): lane (g,c): col c, k = 8g+i.  C/D: col=lane&15, row=4*(l>>4)+reg.
//   - h transpose via tiny per-wave LDS bounce, h rows PACKED (dword at 4c =
//     (h[c],h[c+16])); W2 fragment uses the same k-permutation.

#define N_IN  64
#define N_MID 32
#define N_OUT 10

#define WAVES_PER_BLOCK 4
#define TILES_PER_WAVE  4
#define ROWS_PER_TILE   16
#define ROWS_PER_BLOCK  (WAVES_PER_BLOCK * TILES_PER_WAVE * ROWS_PER_TILE)  // 256
#define H_STRIDE        80        // bytes per h-row in LDS (64 data + 16 pad)
#define XTILE_BYTES     4096      // 16 rows * 256 B
#define ROW_BYTES       256

typedef short bf16x8 __attribute__((ext_vector_type(8)));
typedef float f32x4  __attribute__((ext_vector_type(4)));

typedef __attribute__((address_space(3))) unsigned char       lds_u8_as;
typedef const __attribute__((address_space(1))) unsigned char glb_u8_as;

static __device__ __forceinline__ short f2bf(float f) {
    __bf16 h = (__bf16)f;
    return __builtin_bit_cast(short, h);
}

static __device__ __forceinline__ unsigned pk2bf(float lo, float hi) {
    unsigned l = (unsigned short)__builtin_bit_cast(unsigned short, (__bf16)lo);
    unsigned h = (unsigned short)__builtin_bit_cast(unsigned short, (__bf16)hi);
    return (h << 16) | l;
}

__global__ __launch_bounds__(256)
void livenet_mfma(const float* __restrict__ x,
                  const float* __restrict__ W1,
                  const float* __restrict__ b1,
                  const float* __restrict__ W2,
                  const float* __restrict__ b2,
                  float* __restrict__ out,
                  int batch) {
    __shared__ __align__(16) unsigned char xstage_all[WAVES_PER_BLOCK][2 * XTILE_BYTES];
    __shared__ __align__(16) unsigned char h_lds_all[WAVES_PER_BLOCK][ROWS_PER_TILE * H_STRIDE];

    const int lane = threadIdx.x & 63;
    const int wave = threadIdx.x >> 6;
    const int g    = lane >> 4;   // 0..3 : k-group
    const int c    = lane & 15;   // 0..15: row (A) / col (B,C)

    unsigned char* xstage = xstage_all[wave];
    unsigned char* h_lds  = h_lds_all[wave];

    // ---- weight fragments, once per wave ----
    bf16x8 w1f[2][2];  // [n-tile][k-half]
    #pragma unroll
    for (int n = 0; n < 2; ++n)
        #pragma unroll
        for (int p = 0; p < 2; ++p)
            #pragma unroll
            for (int i = 0; i < 8; ++i) {
                int k = p * 32 + 8 * g + i;
                w1f[n][p][i] = f2bf(W1[k * N_MID + n * 16 + c]);
            }

    // W2 fragment in the PACKED-h k-order: position p holds col (p&1)*16+(p>>1).
    bf16x8 w2f;
    #pragma unroll
    for (int i = 0; i < 8; ++i) {
        int kpos = 8 * g + i;
        int col  = (kpos & 1) * 16 + (kpos >> 1);
        w2f[i] = (c < N_OUT) ? f2bf(W2[col * N_OUT + c]) : (short)0;
    }

    const float b1v0 = b1[c];
    const float b1v1 = b1[16 + c];
    const float b2v  = (c < N_OUT) ? b2[c] : 0.0f;

    // ---- per-lane staging source offsets (swizzled global permutation) ----
    // gload_lds instr j stages rows 4j..4j+3: lane l -> row r = 4j + (l>>4),
    // LDS slot m' = l&15 receives global chunk m' ^ (r&7).
    const int r_lo    = lane >> 4;
    const int mprime  = lane & 15;
    unsigned srcoff[4];
    #pragma unroll
    for (int j = 0; j < 4; ++j) {
        int r = 4 * j + r_lo;
        srcoff[j] = (unsigned)(r * ROW_BYTES + 16 * (mprime ^ (r & 7)));
    }

    // ---- fragment read offsets (swizzled): row c, chunks {2g,2g+1,8+2g,9+2g} ----
    const int cw = c & 7;
    const unsigned rd_a0lo = (unsigned)(c * ROW_BYTES + 16 * ((2 * g)     ^ cw));
    const unsigned rd_a0hi = (unsigned)(c * ROW_BYTES + 16 * ((2 * g + 1) ^ cw));
    const unsigned rd_a1lo = (unsigned)(c * ROW_BYTES + 16 * ((8 + 2 * g) ^ cw));
    const unsigned rd_a1hi = (unsigned)(c * ROW_BYTES + 16 * ((9 + 2 * g) ^ cw));

    const size_t wave_row0 = (size_t)blockIdx.x * ROWS_PER_BLOCK
                           + (size_t)wave * (TILES_PER_WAVE * ROWS_PER_TILE);
    const bool full = (wave_row0 + TILES_PER_WAVE * ROWS_PER_TILE) <= (size_t)batch;

    if (full) {
        const unsigned char* xb = (const unsigned char*)x + wave_row0 * ROW_BYTES;

        // ---- prologue: stage tile 0 into buf 0 ----
        #pragma unroll
        for (int j = 0; j < 4; ++j) {
            __builtin_amdgcn_global_load_lds(
                (glb_u8_as*)(xb + srcoff[j]),
                (lds_u8_as*)(xstage + j * 1024), 16, 0, 0);
        }
        __asm__ volatile("s_waitcnt vmcnt(0)" ::: "memory");
        __builtin_amdgcn_sched_barrier(0);

        #pragma unroll
        for (int t = 0; t < TILES_PER_WAVE; ++t) {
            const unsigned char* xbuf = xstage + (t & 1) * XTILE_BYTES;

            // ---- fragment reads from staged tile (swizzled, ~conflict-free) ----
            const float4 f0 = *(const float4*)(xbuf + rd_a0lo);
            const float4 f1 = *(const float4*)(xbuf + rd_a0hi);
            const float4 f2 = *(const float4*)(xbuf + rd_a1lo);
            const float4 f3 = *(const float4*)(xbuf + rd_a1hi);

            // ---- issue next tile's staging into the other buffer ----
            if (t + 1 < TILES_PER_WAVE) {
                const unsigned char* src = xb + (size_t)(t + 1) * XTILE_BYTES;
                unsigned char* nbuf = xstage + ((t + 1) & 1) * XTILE_BYTES;
                #pragma unroll
                for (int j = 0; j < 4; ++j) {
                    __builtin_amdgcn_global_load_lds(
                        (glb_u8_as*)(src + srcoff[j]),
                        (lds_u8_as*)(nbuf + j * 1024), 16, 0, 0);
                }
            }

            // ---- cvt + layer 1 ----
            bf16x8 a0, a1;
            a0[0] = f2bf(f0.x); a0[1] = f2bf(f0.y); a0[2] = f2bf(f0.z); a0[3] = f2bf(f0.w);
            a0[4] = f2bf(f1.x); a0[5] = f2bf(f1.y); a0[6] = f2bf(f1.z); a0[7] = f2bf(f1.w);
            a1[0] = f2bf(f2.x); a1[1] = f2bf(f2.y); a1[2] = f2bf(f2.z); a1[3] = f2bf(f2.w);
            a1[4] = f2bf(f3.x); a1[5] = f2bf(f3.y); a1[6] = f2bf(f3.z); a1[7] = f2bf(f3.w);

            f32x4 acc0 = {b1v0, b1v0, b1v0, b1v0};
            f32x4 acc1 = {b1v1, b1v1, b1v1, b1v1};
            acc0 = __builtin_amdgcn_mfma_f32_16x16x32_bf16(a0, w1f[0][0], acc0, 0, 0, 0);
            acc0 = __builtin_amdgcn_mfma_f32_16x16x32_bf16(a1, w1f[0][1], acc0, 0, 0, 0);
            acc1 = __builtin_amdgcn_mfma_f32_16x16x32_bf16(a0, w1f[1][0], acc1, 0, 0, 0);
            acc1 = __builtin_amdgcn_mfma_f32_16x16x32_bf16(a1, w1f[1][1], acc1, 0, 0, 0);

            // ---- relu + packed transpose write: dword = (h[c], h[c+16]) ----
            #pragma unroll
            for (int r = 0; r < 4; ++r) {
                const int rowr = 4 * g + r;
                *(unsigned*)(h_lds + rowr * H_STRIDE + 4 * c) =
                    pk2bf(fmaxf(acc0[r], 0.0f), fmaxf(acc1[r], 0.0f));
            }
            __asm__ volatile("" ::: "memory");

            // ---- layer 2 ----
            const bf16x8 hfrag = *(const bf16x8*)(h_lds + c * H_STRIDE + 16 * g);
            f32x4 acc2 = {b2v, b2v, b2v, b2v};
            acc2 = __builtin_amdgcn_mfma_f32_16x16x32_bf16(hfrag, w2f, acc2, 0, 0, 0);

            __asm__ volatile("" ::: "memory");

            // ---- store ----
            if (c < N_OUT) {
                const size_t rb = wave_row0 + (size_t)t * ROWS_PER_TILE;
                float* op = out + (rb + 4 * g) * N_OUT + c;
                op[0 * N_OUT] = acc2[0];
                op[1 * N_OUT] = acc2[1];
                op[2 * N_OUT] = acc2[2];
                op[3 * N_OUT] = acc2[3];
            }

            // ---- wait for next tile's staging; tolerate 4 in-flight stores ----
            if (t + 1 < TILES_PER_WAVE) {
                __asm__ volatile("s_waitcnt vmcnt(4)" ::: "memory");
                __builtin_amdgcn_sched_barrier(0);
            }
        }
    } else {
        // ---- tail path (partial blocks; not taken for batch % 256 == 0) ----
        for (int t = 0; t < TILES_PER_WAVE; ++t) {
            const size_t rb = wave_row0 + (size_t)t * ROWS_PER_TILE;
            if (rb + ROWS_PER_TILE > (size_t)batch) break;

            const float* xp = x + (rb + (size_t)c) * N_IN + 8 * g;
            float4 v0 = *(const float4*)(xp + 0);
            float4 v1 = *(const float4*)(xp + 4);
            float4 v2 = *(const float4*)(xp + 32);
            float4 v3 = *(const float4*)(xp + 36);

            bf16x8 a0, a1;
            a0[0] = f2bf(v0.x); a0[1] = f2bf(v0.y); a0[2] = f2bf(v0.z); a0[3] = f2bf(v0.w);
            a0[4] = f2bf(v1.x); a0[5] = f2bf(v1.y); a0[6] = f2bf(v1.z); a0[7] = f2bf(v1.w);
            a1[0] = f2bf(v2.x); a1[1] = f2bf(v2.y); a1[2] = f2bf(v2.z); a1[3] = f2bf(v2.w);
            a1[4] = f2bf(v3.x); a1[5] = f2bf(v3.y); a1[6] = f2bf(v3.z); a1[7] = f2bf(v3.w);

            f32x4 acc0 = {b1v0, b1v0, b1v0, b1v0};
            f32x4 acc1 = {b1v1, b1v1, b1v1, b1v1};
            acc0 = __builtin_amdgcn_mfma_f32_16x16x32_bf16(a0, w1f[0][0], acc0, 0, 0, 0);
            acc0 = __builtin_amdgcn_mfma_f32_16x16x32_bf16(a1, w1f[0][1], acc0, 0, 0, 0);
            acc1 = __builtin_amdgcn_mfma_f32_16x16x32_bf16(a0, w1f[1][0], acc1, 0, 0, 0);
            acc1 = __builtin_amdgcn_mfma_f32_16x16x32_bf16(a1, w1f[1][1], acc1, 0, 0, 0);

            #pragma unroll
            for (int r = 0; r < 4; ++r) {
                const int rowr = 4 * g + r;
                *(unsigned*)(h_lds + rowr * H_STRIDE + 4 * c) =
                    pk2bf(fmaxf(acc0[r], 0.0f), fmaxf(acc1[r], 0.0f));
            }
            __asm__ volatile("" ::: "memory");

            const bf16x8 hfrag = *(const bf16x8*)(h_lds + c * H_STRIDE + 16 * g);
            f32x4 acc2 = {b2v, b2v, b2v, b2v};
            acc2 = __builtin_amdgcn_mfma_f32_16x16x32_bf16(hfrag, w2f, acc2, 0, 0, 0);

            __asm__ volatile("" ::: "memory");

            if (c < N_OUT) {
                float* op = out + (rb + 4 * g) * N_OUT + c;
                op[0 * N_OUT] = acc2[0];
                op[1 * N_OUT] = acc2[1];
                op[2 * N_OUT] = acc2[2];
                op[3 * N_OUT] = acc2[3];
            }
        }
    }
}

extern "C" void kernel_launch(void* const* d_in, const int* in_sizes, int n_in,
                              void* d_out, int out_size, void* d_ws, size_t ws_size,
                              hipStream_t stream) {
    const float* x  = (const float*)d_in[0];
    const float* W1 = (const float*)d_in[1];
    const float* b1 = (const float*)d_in[2];
    const float* W2 = (const float*)d_in[3];
    const float* b2 = (const float*)d_in[4];
    float* out = (float*)d_out;

    int batch = in_sizes[0] / N_IN;                             // 1048576
    int grid  = (batch + ROWS_PER_BLOCK - 1) / ROWS_PER_BLOCK;  // 4096
    livenet_mfma<<<grid, 256, 0, stream>>>(x, W1, b1, W2, b2, out, batch);
}

// Round 5
// 61.203 us; speedup vs baseline: 1.0878x; 1.0210x over previous
//
#include <hip/hip_runtime.h>

// y = relu(x @ W1 + b1) @ W2 + b2  via bf16 MFMA (fp32 accumulate).
// x: [B, 64] f32, W1: [64, 32], b1: [32], W2: [32, 10], b2: [10], y: [B, 10] f32.
//
// Round 5: prefetch DEPTH 2 (3 LDS staging buffers, 8 tiles/wave).
//   Issue order per wave:  L0 L1 | L2 w0 S0 | L3 w1 S1 | L4 w2 S2 | ... | w6 S6 | w7 S7
//   where Lt = 4x global_load_lds for tile t, St = 4 y-stores, wt = counted
//   s_waitcnt vmcnt(N) guaranteeing Lt complete:
//     w0: newer = {L1,L2}            -> vmcnt(8)
//     w1: newer = {L2,S0,L3}         -> vmcnt(12)
//     w2..w5: newer = {S,L,S,L}      -> vmcnt(16)
//     w6: newer = {S4,L7,S5}         -> vmcnt(12)
//     w7: newer = {S5,S6}            -> vmcnt(8)
//   All constants compile-time (unrolled loop). A miscount -> stale frag reads
//   -> absmax explodes (fail-loud).
//
//   Staging swizzle (rule: both-sides-or-neither): LDS dest LINEAR; global
//   source chunk permuted (chunk m' of row r holds global chunk m'^(r&7));
//   ds_read applies the same XOR -> balanced 8 bank-groups for b128.
//   A-frag: lane (g,c): row c, k=8g+i. C/D: col=lane&15, row=4*(lane>>4)+reg.
//   h bounce: rows PACKED (dword at 4c = (h[c],h[c+16])); W2 frag uses the
//   same k-permutation so the MFMA k-reduction is unchanged.

#define N_IN  64
#define N_MID 32
#define N_OUT 10

#define WAVES_PER_BLOCK 4
#define TILES_PER_WAVE  8
#define ROWS_PER_TILE   16
#define ROWS_PER_BLOCK  (WAVES_PER_BLOCK * TILES_PER_WAVE * ROWS_PER_TILE)  // 512
#define NBUF            3
#define H_STRIDE        80        // bytes per h-row in LDS (64 data + 16 pad)
#define XTILE_BYTES     4096      // 16 rows * 256 B
#define ROW_BYTES       256

typedef short bf16x8 __attribute__((ext_vector_type(8)));
typedef float f32x4  __attribute__((ext_vector_type(4)));

typedef __attribute__((address_space(3))) unsigned char       lds_u8_as;
typedef const __attribute__((address_space(1))) unsigned char glb_u8_as;

static __device__ __forceinline__ short f2bf(float f) {
    __bf16 h = (__bf16)f;
    return __builtin_bit_cast(short, h);
}

static __device__ __forceinline__ unsigned pk2bf(float lo, float hi) {
    unsigned l = (unsigned short)__builtin_bit_cast(unsigned short, (__bf16)lo);
    unsigned h = (unsigned short)__builtin_bit_cast(unsigned short, (__bf16)hi);
    return (h << 16) | l;
}

__global__ __launch_bounds__(256)
void livenet_mfma(const float* __restrict__ x,
                  const float* __restrict__ W1,
                  const float* __restrict__ b1,
                  const float* __restrict__ W2,
                  const float* __restrict__ b2,
                  float* __restrict__ out,
                  int batch) {
    __shared__ __align__(16) unsigned char xstage_all[WAVES_PER_BLOCK][NBUF * XTILE_BYTES];
    __shared__ __align__(16) unsigned char h_lds_all[WAVES_PER_BLOCK][ROWS_PER_TILE * H_STRIDE];

    const int lane = threadIdx.x & 63;
    const int wave = threadIdx.x >> 6;
    const int g    = lane >> 4;   // 0..3 : k-group
    const int c    = lane & 15;   // 0..15: row (A) / col (B,C)

    unsigned char* xstage = xstage_all[wave];
    unsigned char* h_lds  = h_lds_all[wave];

    // ---- weight fragments, once per wave ----
    bf16x8 w1f[2][2];  // [n-tile][k-half]
    #pragma unroll
    for (int n = 0; n < 2; ++n)
        #pragma unroll
        for (int p = 0; p < 2; ++p)
            #pragma unroll
            for (int i = 0; i < 8; ++i) {
                int k = p * 32 + 8 * g + i;
                w1f[n][p][i] = f2bf(W1[k * N_MID + n * 16 + c]);
            }

    // W2 fragment in the PACKED-h k-order: position p holds col (p&1)*16+(p>>1).
    bf16x8 w2f;
    #pragma unroll
    for (int i = 0; i < 8; ++i) {
        int kpos = 8 * g + i;
        int col  = (kpos & 1) * 16 + (kpos >> 1);
        w2f[i] = (c < N_OUT) ? f2bf(W2[col * N_OUT + c]) : (short)0;
    }

    const float b1v0 = b1[c];
    const float b1v1 = b1[16 + c];
    const float b2v  = (c < N_OUT) ? b2[c] : 0.0f;

    // ---- per-lane staging source offsets (swizzled global permutation) ----
    const int r_lo    = lane >> 4;
    const int mprime  = lane & 15;
    unsigned srcoff[4];
    #pragma unroll
    for (int j = 0; j < 4; ++j) {
        int r = 4 * j + r_lo;
        srcoff[j] = (unsigned)(r * ROW_BYTES + 16 * (mprime ^ (r & 7)));
    }

    // ---- fragment read offsets (swizzled): row c, chunks {2g,2g+1,8+2g,9+2g} ----
    const int cw = c & 7;
    const unsigned rd_a0lo = (unsigned)(c * ROW_BYTES + 16 * ((2 * g)     ^ cw));
    const unsigned rd_a0hi = (unsigned)(c * ROW_BYTES + 16 * ((2 * g + 1) ^ cw));
    const unsigned rd_a1lo = (unsigned)(c * ROW_BYTES + 16 * ((8 + 2 * g) ^ cw));
    const unsigned rd_a1hi = (unsigned)(c * ROW_BYTES + 16 * ((9 + 2 * g) ^ cw));

    const size_t wave_row0 = (size_t)blockIdx.x * ROWS_PER_BLOCK
                           + (size_t)wave * (TILES_PER_WAVE * ROWS_PER_TILE);
    const bool full = (wave_row0 + TILES_PER_WAVE * ROWS_PER_TILE) <= (size_t)batch;

    if (full) {
        const unsigned char* xb = (const unsigned char*)x + wave_row0 * ROW_BYTES;

        // ---- prologue: stage tile 0 -> buf 0, tile 1 -> buf 1 ----
        #pragma unroll
        for (int j = 0; j < 4; ++j) {
            __builtin_amdgcn_global_load_lds(
                (glb_u8_as*)(xb + srcoff[j]),
                (lds_u8_as*)(xstage + 0 * XTILE_BYTES + j * 1024), 16, 0, 0);
        }
        #pragma unroll
        for (int j = 0; j < 4; ++j) {
            __builtin_amdgcn_global_load_lds(
                (glb_u8_as*)(xb + XTILE_BYTES + srcoff[j]),
                (lds_u8_as*)(xstage + 1 * XTILE_BYTES + j * 1024), 16, 0, 0);
        }

        #pragma unroll
        for (int t = 0; t < TILES_PER_WAVE; ++t) {
            // ---- issue stage of tile t+2 into buf (t+2)%3 (before the wait) ----
            if (t + 2 < TILES_PER_WAVE) {
                const unsigned char* src = xb + (size_t)(t + 2) * XTILE_BYTES;
                unsigned char* nbuf = xstage + ((t + 2) % NBUF) * XTILE_BYTES;
                #pragma unroll
                for (int j = 0; j < 4; ++j) {
                    __builtin_amdgcn_global_load_lds(
                        (glb_u8_as*)(src + srcoff[j]),
                        (lds_u8_as*)(nbuf + j * 1024), 16, 0, 0);
                }
            }

            // ---- counted wait: guarantee tile t's staging is complete ----
            if (t == 0) {
                __asm__ volatile("s_waitcnt vmcnt(8)" ::: "memory");
            } else if (t == 1) {
                __asm__ volatile("s_waitcnt vmcnt(12)" ::: "memory");
            } else if (t == TILES_PER_WAVE - 2) {
                __asm__ volatile("s_waitcnt vmcnt(12)" ::: "memory");
            } else if (t == TILES_PER_WAVE - 1) {
                __asm__ volatile("s_waitcnt vmcnt(8)" ::: "memory");
            } else {
                __asm__ volatile("s_waitcnt vmcnt(16)" ::: "memory");
            }
            __builtin_amdgcn_sched_barrier(0);

            const unsigned char* xbuf = xstage + (t % NBUF) * XTILE_BYTES;

            // ---- fragment reads from staged tile (swizzled, balanced banks) ----
            const float4 f0 = *(const float4*)(xbuf + rd_a0lo);
            const float4 f1 = *(const float4*)(xbuf + rd_a0hi);
            const float4 f2 = *(const float4*)(xbuf + rd_a1lo);
            const float4 f3 = *(const float4*)(xbuf + rd_a1hi);

            // ---- cvt + layer 1 ----
            bf16x8 a0, a1;
            a0[0] = f2bf(f0.x); a0[1] = f2bf(f0.y); a0[2] = f2bf(f0.z); a0[3] = f2bf(f0.w);
            a0[4] = f2bf(f1.x); a0[5] = f2bf(f1.y); a0[6] = f2bf(f1.z); a0[7] = f2bf(f1.w);
            a1[0] = f2bf(f2.x); a1[1] = f2bf(f2.y); a1[2] = f2bf(f2.z); a1[3] = f2bf(f2.w);
            a1[4] = f2bf(f3.x); a1[5] = f2bf(f3.y); a1[6] = f2bf(f3.z); a1[7] = f2bf(f3.w);

            f32x4 acc0 = {b1v0, b1v0, b1v0, b1v0};
            f32x4 acc1 = {b1v1, b1v1, b1v1, b1v1};
            acc0 = __builtin_amdgcn_mfma_f32_16x16x32_bf16(a0, w1f[0][0], acc0, 0, 0, 0);
            acc0 = __builtin_amdgcn_mfma_f32_16x16x32_bf16(a1, w1f[0][1], acc0, 0, 0, 0);
            acc1 = __builtin_amdgcn_mfma_f32_16x16x32_bf16(a0, w1f[1][0], acc1, 0, 0, 0);
            acc1 = __builtin_amdgcn_mfma_f32_16x16x32_bf16(a1, w1f[1][1], acc1, 0, 0, 0);

            // ---- relu + packed transpose write: dword = (h[c], h[c+16]) ----
            #pragma unroll
            for (int r = 0; r < 4; ++r) {
                const int rowr = 4 * g + r;
                *(unsigned*)(h_lds + rowr * H_STRIDE + 4 * c) =
                    pk2bf(fmaxf(acc0[r], 0.0f), fmaxf(acc1[r], 0.0f));
            }
            __asm__ volatile("" ::: "memory");

            // ---- layer 2 ----
            const bf16x8 hfrag = *(const bf16x8*)(h_lds + c * H_STRIDE + 16 * g);
            f32x4 acc2 = {b2v, b2v, b2v, b2v};
            acc2 = __builtin_amdgcn_mfma_f32_16x16x32_bf16(hfrag, w2f, acc2, 0, 0, 0);

            __asm__ volatile("" ::: "memory");

            // ---- store: exactly 4 VMEM ops per iteration (exec-masked) ----
            if (c < N_OUT) {
                const size_t rb = wave_row0 + (size_t)t * ROWS_PER_TILE;
                float* op = out + (rb + 4 * g) * N_OUT + c;
                op[0 * N_OUT] = acc2[0];
                op[1 * N_OUT] = acc2[1];
                op[2 * N_OUT] = acc2[2];
                op[3 * N_OUT] = acc2[3];
            }
        }
    } else {
        // ---- tail path (partial blocks; not taken: batch % 512 == 0) ----
        for (int t = 0; t < TILES_PER_WAVE; ++t) {
            const size_t rb = wave_row0 + (size_t)t * ROWS_PER_TILE;
            if (rb + ROWS_PER_TILE > (size_t)batch) break;

            const float* xp = x + (rb + (size_t)c) * N_IN + 8 * g;
            float4 v0 = *(const float4*)(xp + 0);
            float4 v1 = *(const float4*)(xp + 4);
            float4 v2 = *(const float4*)(xp + 32);
            float4 v3 = *(const float4*)(xp + 36);

            bf16x8 a0, a1;
            a0[0] = f2bf(v0.x); a0[1] = f2bf(v0.y); a0[2] = f2bf(v0.z); a0[3] = f2bf(v0.w);
            a0[4] = f2bf(v1.x); a0[5] = f2bf(v1.y); a0[6] = f2bf(v1.z); a0[7] = f2bf(v1.w);
            a1[0] = f2bf(v2.x); a1[1] = f2bf(v2.y); a1[2] = f2bf(v2.z); a1[3] = f2bf(v2.w);
            a1[4] = f2bf(v3.x); a1[5] = f2bf(v3.y); a1[6] = f2bf(v3.z); a1[7] = f2bf(v3.w);

            f32x4 acc0 = {b1v0, b1v0, b1v0, b1v0};
            f32x4 acc1 = {b1v1, b1v1, b1v1, b1v1};
            acc0 = __builtin_amdgcn_mfma_f32_16x16x32_bf16(a0, w1f[0][0], acc0, 0, 0, 0);
            acc0 = __builtin_amdgcn_mfma_f32_16x16x32_bf16(a1, w1f[0][1], acc0, 0, 0, 0);
            acc1 = __builtin_amdgcn_mfma_f32_16x16x32_bf16(a0, w1f[1][0], acc1, 0, 0, 0);
            acc1 = __builtin_amdgcn_mfma_f32_16x16x32_bf16(a1, w1f[1][1], acc1, 0, 0, 0);

            #pragma unroll
            for (int r = 0; r < 4; ++r) {
                const int rowr = 4 * g + r;
                *(unsigned*)(h_lds + rowr * H_STRIDE + 4 * c) =
                    pk2bf(fmaxf(acc0[r], 0.0f), fmaxf(acc1[r], 0.0f));
            }
            __asm__ volatile("" ::: "memory");

            const bf16x8 hfrag = *(const bf16x8*)(h_lds + c * H_STRIDE + 16 * g);
            f32x4 acc2 = {b2v, b2v, b2v, b2v};
            acc2 = __builtin_amdgcn_mfma_f32_16x16x32_bf16(hfrag, w2f, acc2, 0, 0, 0);

            __asm__ volatile("" ::: "memory");

            if (c < N_OUT) {
                float* op = out + (rb + 4 * g) * N_OUT + c;
                op[0 * N_OUT] = acc2[0];
                op[1 * N_OUT] = acc2[1];
                op[2 * N_OUT] = acc2[2];
                op[3 * N_OUT] = acc2[3];
            }
        }
    }
}

extern "C" void kernel_launch(void* const* d_in, const int* in_sizes, int n_in,
                              void* d_out, int out_size, void* d_ws, size_t ws_size,
                              hipStream_t stream) {
    const float* x  = (const float*)d_in[0];
    const float* W1 = (const float*)d_in[1];
    const float* b1 = (const float*)d_in[2];
    const float* W2 = (const float*)d_in[3];
    const float* b2 = (const float*)d_in[4];
    float* out = (float*)d_out;

    int batch = in_sizes[0] / N_IN;                             // 1048576
    int grid  = (batch + ROWS_PER_BLOCK - 1) / ROWS_PER_BLOCK;  // 2048
    livenet_mfma<<<grid, 256, 0, stream>>>(x, W1, b1, W2, b2, out, batch);
}